// Round 6
// baseline (683.593 us; speedup 1.0000x reference)
//
#include <hip/hip_runtime.h>

#define NPTS      1048576
#define TABLE_SZ  1048577
#define NLEVELS   3
#define FDIM      8

typedef float f32x4 __attribute__((ext_vector_type(4)));

// One lane per (point, corner): 8 lanes cooperate on one point (best variant, R1).
// All 6 gather dwordx4 per lane issued back-to-back; nontemporal hint on the
// gathers (zero L1 reuse) to keep L1 clean for the coherent index/coord streams.
__global__ __launch_bounds__(256) void octree_gather_kernel(
    const float* __restrict__ coord,     // (NPTS, 3)
    const float* __restrict__ features,  // (NLEVELS, TABLE_SZ, 8)
    const int*   __restrict__ indices,   // (NLEVELS, NPTS, 8)
    float*       __restrict__ out)       // (NPTS, 8)
{
    const int tid    = blockIdx.x * blockDim.x + threadIdx.x;
    const int lane_c = tid & 7;   // corner 0..7
    const int n      = tid >> 3;  // point index

    const float x = coord[3 * n + 0];
    const float y = coord[3 * n + 1];
    const float z = coord[3 * n + 2];

    // ---- load all 3 levels' indices (coalesced: addr = i*NPTS*8 + tid) ----
    int idx[NLEVELS];
    #pragma unroll
    for (int i = 0; i < NLEVELS; ++i)
        idx[i] = indices[(size_t)i * (size_t)NPTS * 8 + (size_t)tid];

    // ---- issue ALL gathers up front (6 dwordx4 in flight per lane) ----
    f32x4 ga[NLEVELS], gb[NLEVELS];
    #pragma unroll
    for (int i = 0; i < NLEVELS; ++i) {
        const float* ft = features + (size_t)(NLEVELS - 1 - i) * (size_t)TABLE_SZ * FDIM;
        const f32x4* gp = reinterpret_cast<const f32x4*>(ft + (size_t)idx[i] * FDIM);
        ga[i] = __builtin_nontemporal_load(gp);
        gb[i] = __builtin_nontemporal_load(gp + 1);
    }

    // ---- compute per-level smoothstep weights (overlaps gather latency) ----
    float w[NLEVELS];
    #pragma unroll
    for (int i = 0; i < NLEVELS; ++i) {
        const float scale = (float)(2048 >> i);  // 2^(level-1), level = 12-i
        float cx = fmaf(scale, x, scale);
        float cy = fmaf(scale, y, scale);
        float cz = fmaf(scale, z, scale);
        float dx = cx - floorf(cx);
        float dy = cy - floorf(cy);
        float dz = cz - floorf(cz);
        dx = dx * dx * (3.0f - 2.0f * dx);
        dy = dy * dy * (3.0f - 2.0f * dy);
        dz = dz * dz * (3.0f - 2.0f * dz);
        // weight order: bit2 -> x, bit1 -> y, bit0 -> z
        float wi = ((lane_c & 4) ? dx : 1.0f - dx)
                 * ((lane_c & 2) ? dy : 1.0f - dy)
                 * ((lane_c & 1) ? dz : 1.0f - dz);
        // reference zeroes features[:, -1, :]: mask the weight instead
        w[i] = (idx[i] == TABLE_SZ - 1) ? 0.0f : wi;
    }

    // ---- weighted accumulate over levels ----
    float acc[FDIM];
    #pragma unroll
    for (int d = 0; d < FDIM; ++d) acc[d] = 0.0f;
    #pragma unroll
    for (int i = 0; i < NLEVELS; ++i) {
        acc[0] = fmaf(w[i], ga[i].x, acc[0]);
        acc[1] = fmaf(w[i], ga[i].y, acc[1]);
        acc[2] = fmaf(w[i], ga[i].z, acc[2]);
        acc[3] = fmaf(w[i], ga[i].w, acc[3]);
        acc[4] = fmaf(w[i], gb[i].x, acc[4]);
        acc[5] = fmaf(w[i], gb[i].y, acc[5]);
        acc[6] = fmaf(w[i], gb[i].z, acc[6]);
        acc[7] = fmaf(w[i], gb[i].w, acc[7]);
    }

    // ---- 3-round shfl_xor transpose-reduce over the 8 corner-lanes ----
    // After the 3 rounds, lane c holds output element c of its point.
    const int b0 = lane_c & 1, b1 = (lane_c >> 1) & 1, b2 = (lane_c >> 2) & 1;

    float s4[4];
    #pragma unroll
    for (int j = 0; j < 4; ++j) {
        float snd  = b0 ? acc[2 * j] : acc[2 * j + 1];
        float got  = __shfl_xor(snd, 1);
        float kept = b0 ? acc[2 * j + 1] : acc[2 * j];
        s4[j] = kept + got;   // element (j<<1)|b0, summed over lane-bit0
    }
    float s2[2];
    #pragma unroll
    for (int j = 0; j < 2; ++j) {
        float snd  = b1 ? s4[2 * j] : s4[2 * j + 1];
        float got  = __shfl_xor(snd, 2);
        float kept = b1 ? s4[2 * j + 1] : s4[2 * j];
        s2[j] = kept + got;   // element (j<<2)|(b1<<1)|b0
    }
    {
        float snd  = b2 ? s2[0] : s2[1];
        float got  = __shfl_xor(snd, 4);
        float kept = b2 ? s2[1] : s2[0];
        float s = kept + got; // element (b2<<2)|(b1<<1)|b0 == lane_c
        out[(size_t)n * FDIM + lane_c] = s;  // coalesced 256B per wave
    }
}

extern "C" void kernel_launch(void* const* d_in, const int* in_sizes, int n_in,
                              void* d_out, int out_size, void* d_ws, size_t ws_size,
                              hipStream_t stream) {
    const float* coord    = (const float*)d_in[0];
    const float* features = (const float*)d_in[1];
    const int*   indices  = (const int*)d_in[2];
    float*       out      = (float*)d_out;

    const int block = 256;
    const long total_threads = (long)NPTS * 8;          // one lane per (point, corner)
    const int grid  = (int)((total_threads + block - 1) / block);  // 32768
    octree_gather_kernel<<<grid, block, 0, stream>>>(coord, features, indices, out);
}

// Round 7
// 450.291 us; speedup vs baseline: 1.5181x; 1.5181x over previous
//
#include <hip/hip_runtime.h>

#define NPTS      1048576
#define TABLE_SZ  1048577
#define NLEVELS   3
#define FDIM      8

// One lane per (point, corner): 8 lanes cooperate on one point.
// tid = point*8 + corner. All index loads and output stores are coalesced;
// each lane issues all 3 levels' gathers back-to-back (6 dwordx4 in flight).
// NOTE: plain (cached) gathers — nontemporal hints regress 1.5x because L2
// retention merges the two half-line dwordx4 loads of each feature row.
__global__ __launch_bounds__(256) void octree_gather_kernel(
    const float* __restrict__ coord,     // (NPTS, 3)
    const float* __restrict__ features,  // (NLEVELS, TABLE_SZ, 8)
    const int*   __restrict__ indices,   // (NLEVELS, NPTS, 8)
    float*       __restrict__ out)       // (NPTS, 8)
{
    const int tid    = blockIdx.x * blockDim.x + threadIdx.x;
    const int lane_c = tid & 7;   // corner 0..7
    const int n      = tid >> 3;  // point index

    const float x = coord[3 * n + 0];
    const float y = coord[3 * n + 1];
    const float z = coord[3 * n + 2];

    // ---- load all 3 levels' indices (coalesced: addr = i*NPTS*8 + tid) ----
    int idx[NLEVELS];
    #pragma unroll
    for (int i = 0; i < NLEVELS; ++i)
        idx[i] = indices[(size_t)i * (size_t)NPTS * 8 + (size_t)tid];

    // ---- issue ALL gathers up front (6 dwordx4 in flight per lane) ----
    float4 ga[NLEVELS], gb[NLEVELS];
    #pragma unroll
    for (int i = 0; i < NLEVELS; ++i) {
        const float* ft = features + (size_t)(NLEVELS - 1 - i) * (size_t)TABLE_SZ * FDIM;
        const float4* gp = reinterpret_cast<const float4*>(ft + (size_t)idx[i] * FDIM);
        ga[i] = gp[0];
        gb[i] = gp[1];
    }

    // ---- compute per-level smoothstep weights (overlaps gather latency) ----
    float w[NLEVELS];
    #pragma unroll
    for (int i = 0; i < NLEVELS; ++i) {
        const float scale = (float)(2048 >> i);  // 2^(level-1), level = 12-i
        float cx = fmaf(scale, x, scale);
        float cy = fmaf(scale, y, scale);
        float cz = fmaf(scale, z, scale);
        float dx = cx - floorf(cx);
        float dy = cy - floorf(cy);
        float dz = cz - floorf(cz);
        dx = dx * dx * (3.0f - 2.0f * dx);
        dy = dy * dy * (3.0f - 2.0f * dy);
        dz = dz * dz * (3.0f - 2.0f * dz);
        // weight order: bit2 -> x, bit1 -> y, bit0 -> z
        float wi = ((lane_c & 4) ? dx : 1.0f - dx)
                 * ((lane_c & 2) ? dy : 1.0f - dy)
                 * ((lane_c & 1) ? dz : 1.0f - dz);
        // reference zeroes features[:, -1, :]: mask the weight instead
        w[i] = (idx[i] == TABLE_SZ - 1) ? 0.0f : wi;
    }

    // ---- weighted accumulate over levels ----
    float acc[FDIM];
    #pragma unroll
    for (int d = 0; d < FDIM; ++d) acc[d] = 0.0f;
    #pragma unroll
    for (int i = 0; i < NLEVELS; ++i) {
        acc[0] = fmaf(w[i], ga[i].x, acc[0]);
        acc[1] = fmaf(w[i], ga[i].y, acc[1]);
        acc[2] = fmaf(w[i], ga[i].z, acc[2]);
        acc[3] = fmaf(w[i], ga[i].w, acc[3]);
        acc[4] = fmaf(w[i], gb[i].x, acc[4]);
        acc[5] = fmaf(w[i], gb[i].y, acc[5]);
        acc[6] = fmaf(w[i], gb[i].z, acc[6]);
        acc[7] = fmaf(w[i], gb[i].w, acc[7]);
    }

    // ---- 3-round shfl_xor transpose-reduce over the 8 corner-lanes ----
    // After the 3 rounds, lane c holds output element c of its point.
    const int b0 = lane_c & 1, b1 = (lane_c >> 1) & 1, b2 = (lane_c >> 2) & 1;

    float s4[4];
    #pragma unroll
    for (int j = 0; j < 4; ++j) {
        float snd  = b0 ? acc[2 * j] : acc[2 * j + 1];
        float got  = __shfl_xor(snd, 1);
        float kept = b0 ? acc[2 * j + 1] : acc[2 * j];
        s4[j] = kept + got;   // element (j<<1)|b0, summed over lane-bit0
    }
    float s2[2];
    #pragma unroll
    for (int j = 0; j < 2; ++j) {
        float snd  = b1 ? s4[2 * j] : s4[2 * j + 1];
        float got  = __shfl_xor(snd, 2);
        float kept = b1 ? s4[2 * j + 1] : s4[2 * j];
        s2[j] = kept + got;   // element (j<<2)|(b1<<1)|b0
    }
    {
        float snd  = b2 ? s2[0] : s2[1];
        float got  = __shfl_xor(snd, 4);
        float kept = b2 ? s2[1] : s2[0];
        float s = kept + got; // element (b2<<2)|(b1<<1)|b0 == lane_c
        out[(size_t)n * FDIM + lane_c] = s;  // coalesced 256B per wave
    }
}

extern "C" void kernel_launch(void* const* d_in, const int* in_sizes, int n_in,
                              void* d_out, int out_size, void* d_ws, size_t ws_size,
                              hipStream_t stream) {
    const float* coord    = (const float*)d_in[0];
    const float* features = (const float*)d_in[1];
    const int*   indices  = (const int*)d_in[2];
    float*       out      = (float*)d_out;

    const int block = 256;
    const long total_threads = (long)NPTS * 8;          // one lane per (point, corner)
    const int grid  = (int)((total_threads + block - 1) / block);  // 32768
    octree_gather_kernel<<<grid, block, 0, stream>>>(coord, features, indices, out);
}